// Round 3
// baseline (49.620 us; speedup 1.0000x reference)
//
#include <hip/hip_runtime.h>

// imgs: (B=8, C=128, H=512, W=512) f32; batch_points: (8,2048,2) int32 [x,y]
// out: (16384, 128) f32 + trailing scalar length=16384
#define NB 8
#define NC 128
#define NH 512
#define NW 512
#define NP 2048

// ---------------- Kernel 1: per-batch counting sort of points by y ----------
// One block per batch. perm[b*NP + sorted_pos] = (y<<20)|(x<<11)|p
__global__ __launch_bounds__(512) void sort_points_kernel(
    const int* __restrict__ pts, unsigned* __restrict__ perm)
{
    int b = blockIdx.x;
    __shared__ unsigned hist[512];
    __shared__ unsigned scan_buf[512];

    int t = threadIdx.x;
    hist[t] = 0;
    __syncthreads();

    unsigned recs[4];
    int base = b * NP;
    #pragma unroll
    for (int i = 0; i < 4; ++i) {
        int p = t + i * 512;
        unsigned x = (unsigned)pts[(base + p) * 2 + 0];
        unsigned y = (unsigned)pts[(base + p) * 2 + 1];
        recs[i] = (y << 20) | (x << 11) | (unsigned)p;
        atomicAdd(&hist[y], 1u);
    }
    __syncthreads();

    // Hillis-Steele inclusive scan over 512 bins -> exclusive offsets
    unsigned own = hist[t];
    scan_buf[t] = own;
    __syncthreads();
    for (int d = 1; d < 512; d <<= 1) {
        unsigned add = (t >= d) ? scan_buf[t - d] : 0u;
        __syncthreads();
        scan_buf[t] += add;
        __syncthreads();
    }
    hist[t] = scan_buf[t] - own;   // exclusive prefix, reused as running offset
    __syncthreads();

    #pragma unroll
    for (int i = 0; i < 4; ++i) {
        unsigned y = recs[i] >> 20;
        unsigned pos = atomicAdd(&hist[y], 1u);
        perm[b * NP + pos] = recs[i];
    }
}

// ---------------- Kernel 2: gather in y-sorted order, scatter rows ----------
__global__ __launch_bounds__(256) void crop_gather_sorted_kernel(
    const float* __restrict__ imgs,
    const unsigned* __restrict__ perm,
    float* __restrict__ out)
{
    int tid = blockIdx.x * 256 + threadIdx.x;
    int srow = tid >> 5;                 // sorted position 0..16383
    int lane = tid & 31;
    int c0 = lane << 2;

    unsigned rec = perm[srow];
    int p = (int)(rec & 0x7FFu);
    int x = (int)((rec >> 11) & 0x1FFu);
    int y = (int)(rec >> 20);
    int b = srow >> 11;

    const size_t plane = (size_t)NH * NW;
    const float* src = imgs + ((size_t)(b * NC + c0)) * plane
                            + (size_t)y * NW + (size_t)x;
    float4 v;
    v.x = src[0];
    v.y = src[plane];
    v.z = src[2 * plane];
    v.w = src[3 * plane];

    // scatter to original row; each row's 512B stays contiguous/full-line
    size_t orow = (size_t)(b * NP + p);
    *reinterpret_cast<float4*>(out + orow * NC + c0) = v;

    if (tid == 0) {
        out[(size_t)NB * NP * NC] = 16384.0f;
    }
}

// ---------------- Fallback (unsorted) if workspace is too small -------------
__global__ __launch_bounds__(256) void crop_gather_kernel(
    const float* __restrict__ imgs,
    const int* __restrict__ pts,
    float* __restrict__ out)
{
    int tid = blockIdx.x * 256 + threadIdx.x;
    int row = tid >> 5;
    int t = tid & 31;
    int c0 = t << 2;

    int x = pts[row * 2 + 0];
    int y = pts[row * 2 + 1];
    int b = row >> 11;

    const size_t plane = (size_t)NH * NW;
    const float* src = imgs + ((size_t)(b * NC + c0)) * plane
                            + (size_t)y * NW + (size_t)x;
    float4 v;
    v.x = src[0];
    v.y = src[plane];
    v.z = src[2 * plane];
    v.w = src[3 * plane];
    *reinterpret_cast<float4*>(out + (size_t)row * NC + c0) = v;

    if (tid == 0) {
        out[(size_t)NB * NP * NC] = 16384.0f;
    }
}

extern "C" void kernel_launch(void* const* d_in, const int* in_sizes, int n_in,
                              void* d_out, int out_size, void* d_ws, size_t ws_size,
                              hipStream_t stream) {
    const float* imgs = (const float*)d_in[0];
    const int* pts = (const int*)d_in[1];
    float* out = (float*)d_out;

    const int total_threads = NB * NP * NC / 4;   // 524288
    const int grid = total_threads / 256;         // 2048

    if (ws_size >= (size_t)NB * NP * sizeof(unsigned)) {
        unsigned* perm = (unsigned*)d_ws;
        sort_points_kernel<<<NB, 512, 0, stream>>>(pts, perm);
        crop_gather_sorted_kernel<<<grid, 256, 0, stream>>>(imgs, perm, out);
    } else {
        crop_gather_kernel<<<grid, 256, 0, stream>>>(imgs, pts, out);
    }
}

// Round 4
// 46.722 us; speedup vs baseline: 1.0620x; 1.0620x over previous
//
#include <hip/hip_runtime.h>

// Problem constants (from reference setup_inputs):
//   imgs: (B=8, C=128, H=512, W=512) float32  (1 GiB)
//   batch_points: (B=8, P=2048, 2) — declared int64 but JAX x64 is disabled,
//                 so the actual array is INT32 (harness: integer -> const int*).
//   out: (B*P, C) float32 = (16384, 128)  + scalar length=16384 appended
//
// Roofline note (R2/R3 evidence): pure random gather, zero reuse. Mandatory
// HBM fetch ~237 MB (128B-line amplification of 2M random 4B reads); at
// 6.3 TB/s ideal = 37.6 us. This kernel: 46.7 us (~80% of ideal; remainder is
// random-access DRAM page overhead). R3's y-sorted variant recovered ~11%
// fetch via line dedupe but its sort+scatter cost exceeded the gain (49.6 us).
#define NB 8
#define NC 128
#define NH 512
#define NW 512
#define NP 2048

__global__ __launch_bounds__(256) void crop_gather_kernel(
    const float* __restrict__ imgs,
    const int* __restrict__ pts,         // (B*P, 2) int32: [x, y]
    float* __restrict__ out)
{
    // One thread handles 4 consecutive channels of one output row.
    // 32 threads per row -> float4 coalesced output stores.
    int tid = blockIdx.x * 256 + threadIdx.x;        // 0 .. B*P*C/4-1
    int row = tid >> 5;                              // b*P + p  (0..16383)
    int t   = tid & 31;
    int c0  = t << 2;                                // channel base 0..124

    int x = pts[row * 2 + 0];                        // W index
    int y = pts[row * 2 + 1];                        // H index
    int b = row >> 11;                               // row / P

    const size_t plane = (size_t)NH * NW;            // 262144
    const float* src = imgs + ((size_t)(b * NC + c0)) * plane
                            + (size_t)y * NW + (size_t)x;

    // 4 independent 1MiB-strided loads in flight per thread.
    float4 v;
    v.x = src[0];
    v.y = src[plane];
    v.z = src[2 * plane];
    v.w = src[3 * plane];

    *reinterpret_cast<float4*>(out + (size_t)row * NC + c0) = v;

    // Second tuple element: length = B*P = 16384, stored as float after out.
    if (tid == 0) {
        out[(size_t)NB * NP * NC] = 16384.0f;
    }
}

extern "C" void kernel_launch(void* const* d_in, const int* in_sizes, int n_in,
                              void* d_out, int out_size, void* d_ws, size_t ws_size,
                              hipStream_t stream) {
    const float* imgs = (const float*)d_in[0];
    const int* pts = (const int*)d_in[1];
    float* out = (float*)d_out;

    const int total_threads = NB * NP * NC / 4;      // 524288
    const int block = 256;
    const int grid = total_threads / block;          // 2048

    crop_gather_kernel<<<grid, block, 0, stream>>>(imgs, pts, out);
}